// Round 1
// 447.069 us; speedup vs baseline: 1.1815x; 1.1815x over previous
//
#include <hip/hip_runtime.h>

// GCSA: x(8,192,128,128) fp32 -> qkv 1x1 (MFMA) -> dw3x3 dil2 (vectorized) ->
//       channel attn -> proj folded into M -> out = M·v_post (MFMA).
// qkv_pre bf16 in ws; v_post bf16 overwrites the q-slot after k2 consumed it.
// k2: conv q/k -> bf16 LDS -> 48x48 Gram via MFMA (qq/kk diag gives norms).

#define DIM 192
#define NH 8
#define CH 24
#define IH 128
#define IW 128
#define NPIX (IH*IW)
#define BATCH 8
#define QKVC (3*DIM)
#define PAD 200    // u16 row stride for MFMA LDS tiles (400 B)
#define TPAD 136   // u16 row stride for k1 transpose tile (272 B, 16B-aligned)
#define SPAD 264   // u16 row stride for k2 bf16 tile (528 B, 16B-aligned)

typedef unsigned short u16;
typedef short bf16x8 __attribute__((ext_vector_type(8)));
typedef float f32x4 __attribute__((ext_vector_type(4)));

__device__ __forceinline__ float b2f(u16 u){
    unsigned v = ((unsigned)u) << 16;
    return __builtin_bit_cast(float, v);
}
__device__ __forceinline__ u16 f2b(float f){          // round-to-nearest-even
    unsigned u = __builtin_bit_cast(unsigned, f);
    u += 0x7fffu + ((u >> 16) & 1u);
    return (u16)(u >> 16);
}

// accumulate one conv row (3 taps, dilation 2) for 8 consecutive px at px0
__device__ __forceinline__ void conv_row8(const u16* __restrict__ rp, int px0,
        float w0, float w1, float w2, float* o_){
    float f[12];
    if(px0 > 0){
        unsigned u = *(const unsigned*)(rp + px0 - 2);
        f[0] = b2f((u16)u); f[1] = b2f((u16)(u >> 16));
    } else { f[0] = 0.f; f[1] = 0.f; }
    bf16x8 v = *(const bf16x8*)(rp + px0);
    #pragma unroll
    for(int j=0;j<8;j++) f[2+j] = b2f((u16)v[j]);
    if(px0 < 120){
        unsigned u = *(const unsigned*)(rp + px0 + 8);
        f[10] = b2f((u16)u); f[11] = b2f((u16)(u >> 16));
    } else { f[10] = 0.f; f[11] = 0.f; }
    #pragma unroll
    for(int i=0;i<8;i++) o_[i] += w0*f[i] + w1*f[i+2] + w2*f[i+4];
}

// ---------------------------------------------------------------------------
// K1: qkv_pre[b][o][p] = sum_c Wqkv[o][c]*x[b][c][p].  MFMA 16x16x32 bf16.
// Block: 256 thr, N=128 px staged ONCE, loop 9 o-tiles of 64. grid (128,8).
// ---------------------------------------------------------------------------
__global__ __launch_bounds__(256) void k1_qkv(const float* __restrict__ x,
        const float* __restrict__ wqkv, u16* __restrict__ qkv_pre){
    __shared__ __align__(16) u16 Xl[128*PAD];   // 51.2 KB
    __shared__ __align__(16) u16 Wl[64*PAD];    // 25.6 KB (reused as Tl[64*TPAD])
    const int tid = threadIdx.x;
    const int pt = blockIdx.x, b = blockIdx.y;
    const int p0 = pt*128;
    // stage X^T: Xl[px][c] (coalesced fp32 column loads, packed b128 writes)
    {
        const int px = tid & 127, half = tid >> 7;
        const float* xb = x + (size_t)b*DIM*NPIX + p0 + px;
        for(int cg = 0; cg < 12; cg++){
            int cb = half*96 + cg*8;
            bf16x8 v;
            #pragma unroll
            for(int j=0;j<8;j++) v[j] = (short)f2b(xb[(size_t)(cb+j)*NPIX]);
            *(bf16x8*)&Xl[px*PAD + cb] = v;
        }
    }
    const int lane = tid & 63, w = tid >> 6;
    const int r = lane & 15, quad = lane >> 4;
    const int mbase = (w & 1)*32, nbase = (w >> 1)*64;
    u16* Tl = Wl;
    for(int ot = 0; ot < 9; ot++){
        const int obase = ot*64;
        for(int i = tid; i < 64*24; i += 256){
            int o = i/24, k8 = (i%24)*8;
            const float* wp = wqkv + (size_t)(obase+o)*DIM + k8;
            bf16x8 v;
            #pragma unroll
            for(int j=0;j<8;j++) v[j] = (short)f2b(wp[j]);
            *(bf16x8*)&Wl[o*PAD + k8] = v;
        }
        __syncthreads();   // Wl ready (and Xl on ot=0)
        f32x4 acc[8];
        { f32x4 z = {0.f,0.f,0.f,0.f}; for(int i=0;i<8;i++) acc[i]=z; }
        #pragma unroll
        for(int kk = 0; kk < 6; kk++){
            const int k0 = kk*32 + quad*8;
            bf16x8 a0 = *(const bf16x8*)&Wl[(mbase + r)*PAD + k0];
            bf16x8 a1 = *(const bf16x8*)&Wl[(mbase + 16 + r)*PAD + k0];
            #pragma unroll
            for(int ni=0; ni<4; ni++){
                bf16x8 bb = *(const bf16x8*)&Xl[(nbase + ni*16 + r)*PAD + k0];
                acc[ni*2+0] = __builtin_amdgcn_mfma_f32_16x16x32_bf16(a0, bb, acc[ni*2+0], 0,0,0);
                acc[ni*2+1] = __builtin_amdgcn_mfma_f32_16x16x32_bf16(a1, bb, acc[ni*2+1], 0,0,0);
            }
        }
        __syncthreads();   // done reading Wl -> can overwrite with Tl
        #pragma unroll
        for(int ni=0; ni<4; ni++)
            #pragma unroll
            for(int mi=0; mi<2; mi++){
                int o_loc = mbase + mi*16 + quad*4;
                int p_loc = nbase + ni*16 + r;
                #pragma unroll
                for(int t=0;t<4;t++)
                    Tl[(o_loc+t)*TPAD + p_loc] = f2b(acc[ni*2+mi][t]);
            }
        __syncthreads();   // Tl ready
        u16* op = qkv_pre + ((size_t)b*QKVC + obase)*NPIX + p0;
        for(int it = 0; it < 4; it++){
            int idx = tid + it*256;          // 1024 b128 chunks
            int o = idx >> 4, oct = idx & 15;
            bf16x8 v = *(const bf16x8*)&Tl[o*TPAD + oct*8];
            *(bf16x8*)&op[(size_t)o*NPIX + oct*8] = v;
        }
        __syncthreads();   // done reading Tl -> next ot may overwrite Wl
    }
}

// ---------------------------------------------------------------------------
// K2: per (b,h): full 48x48 Gram of S=[q;k] (conv outputs, bf16) via MFMA.
//   - conv 48 ch x 256 px chunk -> bf16 LDS tile Sl[48][SPAD]
//   - 4 waves K-split (64 px each), 6 upper-triangle 16x16 tiles in regs
//   - 2 chunks/block, LDS reduce of 4 wave-partials, atomicAdd into G.
//   qq/kk diagonals of G supply the L2 norms (sqq/sqk pass deleted).
// grid (32 pchunk, 8 h, 8 b).  LDS 25.3 KB -> 6 blocks/CU.
// ---------------------------------------------------------------------------
__global__ __launch_bounds__(256) void k2_gram(const u16* __restrict__ qkv_pre,
        const float* __restrict__ wdw, float* __restrict__ G){
    __shared__ __align__(16) u16 Sl[48*SPAD];   // 25,344 B; reused as R[4][1536] f32
    const int tid = threadIdx.x;
    const int pc = blockIdx.x, h = blockIdx.y, b = blockIdx.z;
    const int lane = tid & 63, w = tid >> 6;
    const int r = lane & 15, quad = lane >> 4;
    f32x4 acc[6];
    { f32x4 z = {0.f,0.f,0.f,0.f}; for(int i=0;i<6;i++) acc[i]=z; }
    for(int chunk = 0; chunk < 2; chunk++){
        if(chunk) __syncthreads();     // prev MFMA reads of Sl done
        for(int it = 0; it < 6; it++){
            int t = tid + it*256;                 // 0..1535
            int c48 = t >> 5, oct = t & 31;
            int isK = (c48 >= CH);
            int c = isK ? (c48 - CH) : c48;
            int ch = (isK ? DIM : 0) + h*CH + c;
            const u16* base = qkv_pre + ((size_t)b*QKVC + ch)*NPIX;
            const float* wv = wdw + ch*9;
            int py = pc*4 + chunk*2 + (oct >> 4);
            int px0 = (oct & 15)*8;
            float o_[8];
            #pragma unroll
            for(int i=0;i<8;i++) o_[i]=0.f;
            #pragma unroll
            for(int ky=0;ky<3;ky++){
                int ry = py + 2*ky - 2;
                if(ry < 0 || ry >= IH) continue;
                conv_row8(base + ry*IW, px0, wv[ky*3], wv[ky*3+1], wv[ky*3+2], o_);
            }
            bf16x8 v;
            #pragma unroll
            for(int i=0;i<8;i++) v[i] = (short)f2b(o_[i]);
            *(bf16x8*)&Sl[c48*SPAD + oct*8] = v;   // col = within-chunk px idx
        }
        __syncthreads();               // Sl ready
        #pragma unroll
        for(int kk = 0; kk < 2; kk++){
            const int k0 = w*64 + kk*32 + quad*8;
            bf16x8 f0 = *(const bf16x8*)&Sl[(     r)*SPAD + k0];
            bf16x8 f1 = *(const bf16x8*)&Sl[(16 + r)*SPAD + k0];
            bf16x8 f2 = *(const bf16x8*)&Sl[(32 + r)*SPAD + k0];
            acc[0] = __builtin_amdgcn_mfma_f32_16x16x32_bf16(f0, f0, acc[0], 0,0,0);
            acc[1] = __builtin_amdgcn_mfma_f32_16x16x32_bf16(f0, f1, acc[1], 0,0,0);
            acc[2] = __builtin_amdgcn_mfma_f32_16x16x32_bf16(f0, f2, acc[2], 0,0,0);
            acc[3] = __builtin_amdgcn_mfma_f32_16x16x32_bf16(f1, f1, acc[3], 0,0,0);
            acc[4] = __builtin_amdgcn_mfma_f32_16x16x32_bf16(f1, f2, acc[4], 0,0,0);
            acc[5] = __builtin_amdgcn_mfma_f32_16x16x32_bf16(f2, f2, acc[5], 0,0,0);
        }
    }
    __syncthreads();                   // all MFMA reads of Sl done
    float* R = (float*)Sl;             // R[w][tile][lane][t]
    #pragma unroll
    for(int tile=0; tile<6; tile++)
        *(f32x4*)&R[(w*6 + tile)*256 + lane*4] = acc[tile];
    __syncthreads();
    float* Gb = G + (size_t)(b*NH + h)*48*48;
    #pragma unroll
    for(int i=0; i<6; i++){
        int idx = tid + i*256;                    // 0..1535
        int tile = idx >> 8, rem = idx & 255;
        int ln = rem >> 2, t = rem & 3;
        float s = R[idx] + R[1536 + idx] + R[2*1536 + idx] + R[3*1536 + idx];
        int ti = (tile<3) ? 0 : ((tile<5) ? 1 : 2);
        int tj = (tile<3) ? tile : ((tile<5) ? (tile-2) : 2);
        int c = ti*16 + (ln >> 4)*4 + t;
        int d = tj*16 + (ln & 15);
        atomicAdd(&Gb[c*48 + d], s);
    }
}

// ---------------------------------------------------------------------------
// K4: v_post = dw-conv(v_pre), vectorized; written over the q-slot (ch 0..191)
// of qkv_pre (k2 already consumed q). grid (8 bands, 96 chpairs, 8 b).
// thread = (16 py rows x 16 px octets), 2 channels each.
// ---------------------------------------------------------------------------
__global__ __launch_bounds__(256) void k4_vconv(u16* __restrict__ qkv_pre,
        const float* __restrict__ wdw){
    const int tid = threadIdx.x;
    const int oct = tid & 15, pyl = tid >> 4;
    const int band = blockIdx.x, cp = blockIdx.y, b = blockIdx.z;
    const int py = band*16 + pyl, px0 = oct*8;
    #pragma unroll
    for(int j=0;j<2;j++){
        int ch = cp*2 + j;
        const u16* base = qkv_pre + ((size_t)b*QKVC + 2*DIM + ch)*NPIX;
        const float* wv = wdw + (2*DIM + ch)*9;
        float o_[8];
        #pragma unroll
        for(int i=0;i<8;i++) o_[i]=0.f;
        #pragma unroll
        for(int ky=0;ky<3;ky++){
            int ry = py + 2*ky - 2;
            if(ry < 0 || ry >= IH) continue;
            conv_row8(base + ry*IW, px0, wv[ky*3], wv[ky*3+1], wv[ky*3+2], o_);
        }
        bf16x8 v;
        #pragma unroll
        for(int i=0;i<8;i++) v[i] = (short)f2b(o_[i]);
        *(bf16x8*)&qkv_pre[((size_t)b*QKVC + ch)*NPIX + py*IW + px0] = v;
    }
}

// ---------------------------------------------------------------------------
// K3: softmax(Gqk/(|q||k|)*T) folded with Wproj -> M[b][o][hd]. grid 8.
// norms come from the qq/kk diagonals of the 48x48 Gram.
// ---------------------------------------------------------------------------
__global__ __launch_bounds__(256) void k3_attn(const float* __restrict__ G,
        const float* __restrict__ temp, const float* __restrict__ wproj,
        float* __restrict__ M){
    __shared__ float attn[NH][CH][CH];
    __shared__ float nq[DIM], nk[DIM];
    const int b = blockIdx.x, tid = threadIdx.x;
    const float* Gb = G + (size_t)b*NH*48*48;
    if(tid < DIM){
        int h = tid / CH, c = tid % CH;
        const float* g = Gb + (size_t)h*48*48;
        nq[tid] = fmaxf(sqrtf(g[c*48 + c]), 1e-12f);
        nk[tid] = fmaxf(sqrtf(g[(CH+c)*48 + (CH+c)]), 1e-12f);
    }
    __syncthreads();
    if(tid < DIM){
        int h = tid / CH, c = tid % CH;
        float t = temp[h];
        const float* g = Gb + (size_t)h*48*48 + c*48 + CH;   // q row c vs k cols
        float row[CH];
        float mx = -1e30f;
        #pragma unroll
        for(int d=0; d<CH; d++){
            float v = g[d] / (nq[tid]*nk[h*CH+d]) * t;
            row[d]=v; mx = fmaxf(mx,v);
        }
        float sum=0.f;
        #pragma unroll
        for(int d=0;d<CH;d++){ row[d]=expf(row[d]-mx); sum+=row[d]; }
        float inv = 1.f/sum;
        #pragma unroll
        for(int d=0;d<CH;d++) attn[h][c][d] = row[d]*inv;
    }
    __syncthreads();
    float* Mb = M + (size_t)b*DIM*DIM;
    for(int i = tid; i < DIM*DIM; i += 256){
        int o = i / DIM, hd = i % DIM;
        int h = hd / CH, d = hd % CH;
        float s = 0.f;
        #pragma unroll
        for(int c=0;c<CH;c++)
            s += wproj[o*DIM + h*CH + c] * attn[h][c][d];
        Mb[i] = s;
    }
}

// ---------------------------------------------------------------------------
// K5: out[b][o][p] = sum_hd M[b][o][hd]*v_post[b][hd][p].  Pure MFMA GEMM.
// vl staged once (coalesced u16 column loads), loop 3 o-tiles. grid (128,8).
// ---------------------------------------------------------------------------
__global__ __launch_bounds__(256) void k5_out(const u16* __restrict__ qkv_pre,
        const float* __restrict__ M, float* __restrict__ out){
    __shared__ __align__(16) u16 vl[128*PAD];   // 51.2 KB
    __shared__ __align__(16) u16 Ml[64*PAD];    // 25.6 KB
    const int tid = threadIdx.x;
    const int py = blockIdx.x, b = blockIdx.y;
    const int p0 = py*IW;
    // stage v^T: vl[px][ch] from v_post (q-slot, ch 0..191)
    {
        const int px = tid & 127, half = tid >> 7;
        const u16* vb = qkv_pre + (size_t)b*QKVC*NPIX + p0 + px;
        for(int cg = 0; cg < 12; cg++){
            int cb = half*96 + cg*8;
            bf16x8 v;
            #pragma unroll
            for(int j=0;j<8;j++) v[j] = (short)vb[(size_t)(cb+j)*NPIX];
            *(bf16x8*)&vl[px*PAD + cb] = v;
        }
    }
    const int lane = tid & 63, w = tid >> 6;
    const int r = lane & 15, quad = lane >> 4;
    const int mbase = (w & 1)*32, nbase = (w >> 1)*64;
    for(int ot = 0; ot < 3; ot++){
        const int obase = ot*64;
        for(int i = tid; i < 64*24; i += 256){
            int o = i/24, k8 = (i%24)*8;
            const float* mp = M + ((size_t)b*DIM + obase + o)*DIM + k8;
            bf16x8 v;
            #pragma unroll
            for(int j=0;j<8;j++) v[j] = (short)f2b(mp[j]);
            *(bf16x8*)&Ml[o*PAD + k8] = v;
        }
        __syncthreads();   // Ml ready (and vl on ot=0)
        f32x4 acc[8];
        { f32x4 z = {0.f,0.f,0.f,0.f}; for(int i=0;i<8;i++) acc[i]=z; }
        #pragma unroll
        for(int kk = 0; kk < 6; kk++){
            const int k0 = kk*32 + quad*8;
            bf16x8 a0 = *(const bf16x8*)&Ml[(mbase + r)*PAD + k0];
            bf16x8 a1 = *(const bf16x8*)&Ml[(mbase + 16 + r)*PAD + k0];
            #pragma unroll
            for(int ni=0; ni<4; ni++){
                bf16x8 bb = *(const bf16x8*)&vl[(nbase + ni*16 + r)*PAD + k0];
                acc[ni*2+0] = __builtin_amdgcn_mfma_f32_16x16x32_bf16(a0, bb, acc[ni*2+0], 0,0,0);
                acc[ni*2+1] = __builtin_amdgcn_mfma_f32_16x16x32_bf16(a1, bb, acc[ni*2+1], 0,0,0);
            }
        }
        float* op = out + ((size_t)b*DIM + obase)*NPIX + p0;
        #pragma unroll
        for(int ni=0; ni<4; ni++)
            #pragma unroll
            for(int mi=0; mi<2; mi++){
                int o_loc = mbase + mi*16 + quad*4;
                int p_loc = nbase + ni*16 + r;
                #pragma unroll
                for(int t=0;t<4;t++)
                    op[(size_t)(o_loc+t)*NPIX + p_loc] = acc[ni*2+mi][t];
            }
        __syncthreads();   // done with Ml -> next ot restages
    }
}

// ---------------------------------------------------------------------------
extern "C" void kernel_launch(void* const* d_in, const int* in_sizes, int n_in,
                              void* d_out, int out_size, void* d_ws, size_t ws_size,
                              hipStream_t stream){
    const float* x     = (const float*)d_in[0];
    const float* wqkv  = (const float*)d_in[1];
    const float* wdw   = (const float*)d_in[2];
    const float* wproj = (const float*)d_in[3];
    const float* temp  = (const float*)d_in[4];
    float* out = (float*)d_out;

    char* ws = (char*)d_ws;
    u16* qkv_pre = (u16*)ws;                                     // 151 MB
    size_t off = (size_t)BATCH*QKVC*NPIX*sizeof(u16);
    float* G   = (float*)(ws + off); off += (size_t)BATCH*NH*48*48*4;
    float* M   = (float*)(ws + off); off += (size_t)BATCH*DIM*DIM*4;

    hipMemsetAsync(G, 0, (size_t)BATCH*NH*48*48*sizeof(float), stream);

    k1_qkv <<<dim3(128, BATCH), 256, 0, stream>>>(x, wqkv, qkv_pre);
    k2_gram<<<dim3(32, NH, BATCH), 256, 0, stream>>>(qkv_pre, wdw, G);
    // k4 overwrites q-slot with v_post -- must run AFTER k2 consumed q.
    k4_vconv<<<dim3(8, 96, BATCH), 256, 0, stream>>>(qkv_pre, wdw);
    k3_attn<<<BATCH, 256, 0, stream>>>(G, temp, wproj, M);
    k5_out <<<dim3(128, BATCH), 256, 0, stream>>>(qkv_pre, M, out);
}

// Round 2
// 433.835 us; speedup vs baseline: 1.2175x; 1.0305x over previous
//
#include <hip/hip_runtime.h>

// GCSA: x(8,192,128,128) fp32 -> qkv 1x1 (MFMA) -> dw3x3 dil2 (vectorized) ->
//       channel attn -> proj folded into M -> out = M·v_post (MFMA).
// qkv_pre bf16 in ws; v_post bf16 overwrites the q-slot after k2 consumed it.
// k0 pre-converts W to bf16; k1/k5 read A-fragments straight from global (L2)
// and store via swapped-operand MFMA layout -> no W/M staging, no transpose
// LDS, 1 barrier per kernel, 3 blocks/CU.

#define DIM 192
#define NH 8
#define CH 24
#define IH 128
#define IW 128
#define NPIX (IH*IW)
#define BATCH 8
#define QKVC (3*DIM)
#define PAD 200    // u16 row stride for MFMA LDS tiles (400 B)
#define SPAD 264   // u16 row stride for k2 bf16 tile (528 B, 16B-aligned)

typedef unsigned short u16;
typedef short bf16x8 __attribute__((ext_vector_type(8)));
typedef float f32x4 __attribute__((ext_vector_type(4)));

__device__ __forceinline__ float b2f(u16 u){
    unsigned v = ((unsigned)u) << 16;
    return __builtin_bit_cast(float, v);
}
__device__ __forceinline__ u16 f2b(float f){          // round-to-nearest-even
    unsigned u = __builtin_bit_cast(unsigned, f);
    u += 0x7fffu + ((u >> 16) & 1u);
    return (u16)(u >> 16);
}

// accumulate one conv row (3 taps, dilation 2) for 8 consecutive px at px0
__device__ __forceinline__ void conv_row8(const u16* __restrict__ rp, int px0,
        float w0, float w1, float w2, float* o_){
    float f[12];
    if(px0 > 0){
        unsigned u = *(const unsigned*)(rp + px0 - 2);
        f[0] = b2f((u16)u); f[1] = b2f((u16)(u >> 16));
    } else { f[0] = 0.f; f[1] = 0.f; }
    bf16x8 v = *(const bf16x8*)(rp + px0);
    #pragma unroll
    for(int j=0;j<8;j++) f[2+j] = b2f((u16)v[j]);
    if(px0 < 120){
        unsigned u = *(const unsigned*)(rp + px0 + 8);
        f[10] = b2f((u16)u); f[11] = b2f((u16)(u >> 16));
    } else { f[10] = 0.f; f[11] = 0.f; }
    #pragma unroll
    for(int i=0;i<8;i++) o_[i] += w0*f[i] + w1*f[i+2] + w2*f[i+4];
}

// ---------------------------------------------------------------------------
// K0: wqkv fp32 -> bf16 once (576x192 = 110592 elems). grid 108x256x4.
// ---------------------------------------------------------------------------
__global__ __launch_bounds__(256) void k0_wcvt(const float* __restrict__ wqkv,
        u16* __restrict__ wb){
    int i = (blockIdx.x*256 + threadIdx.x)*4;
    f32x4 v = *(const f32x4*)&wqkv[i];
    unsigned lo = ((unsigned)f2b(v[1]) << 16) | f2b(v[0]);
    unsigned hi = ((unsigned)f2b(v[3]) << 16) | f2b(v[2]);
    *(uint2*)&wb[i] = make_uint2(lo, hi);
}

// ---------------------------------------------------------------------------
// K1: qkv_pre[b][o][p] = sum_c Wqkv[o][c]*x[b][c][p].  MFMA 16x16x32 bf16.
// X^T staged once in LDS (51.2 KB -> 3 blocks/CU); W bf16 fragments loaded
// directly from global (L2-resident). Swapped operands: D[px][o] -> lane
// holds 4 consecutive px -> packed 8B global stores. No loop barriers.
// grid (128,8).
// ---------------------------------------------------------------------------
__global__ __launch_bounds__(256) void k1_qkv(const float* __restrict__ x,
        const u16* __restrict__ wb, u16* __restrict__ qkv_pre){
    __shared__ __align__(16) u16 Xl[128*PAD];   // 51.2 KB
    const int tid = threadIdx.x;
    const int pt = blockIdx.x, b = blockIdx.y;
    const int p0 = pt*128;
    // stage X^T: Xl[px][c] (coalesced fp32 column loads, packed b128 writes)
    {
        const int px = tid & 127, half = tid >> 7;
        const float* xb = x + (size_t)b*DIM*NPIX + p0 + px;
        for(int cg = 0; cg < 12; cg++){
            int cb = half*96 + cg*8;
            bf16x8 v;
            #pragma unroll
            for(int j=0;j<8;j++) v[j] = (short)f2b(xb[(size_t)(cb+j)*NPIX]);
            *(bf16x8*)&Xl[px*PAD + cb] = v;
        }
    }
    __syncthreads();
    const int lane = tid & 63, w = tid >> 6;
    const int r = lane & 15, quad = lane >> 4;
    const int mbase = (w & 1)*32, nbase = (w >> 1)*64;
    u16* op = qkv_pre + (size_t)b*QKVC*NPIX + p0;
    for(int ot = 0; ot < 9; ot++){
        const int obase = ot*64;
        f32x4 acc[8];
        { f32x4 z = {0.f,0.f,0.f,0.f}; for(int i=0;i<8;i++) acc[i]=z; }
        const u16* w0p = wb + (size_t)(obase + mbase + r)*DIM;
        const u16* w1p = w0p + 16*DIM;
        #pragma unroll
        for(int kk = 0; kk < 6; kk++){
            const int k0 = kk*32 + quad*8;
            bf16x8 a0 = *(const bf16x8*)&w0p[k0];
            bf16x8 a1 = *(const bf16x8*)&w1p[k0];
            #pragma unroll
            for(int ni=0; ni<4; ni++){
                bf16x8 bb = *(const bf16x8*)&Xl[(nbase + ni*16 + r)*PAD + k0];
                // swapped: D[row=px_sub][col=o_sub]
                acc[ni*2+0] = __builtin_amdgcn_mfma_f32_16x16x32_bf16(bb, a0, acc[ni*2+0], 0,0,0);
                acc[ni*2+1] = __builtin_amdgcn_mfma_f32_16x16x32_bf16(bb, a1, acc[ni*2+1], 0,0,0);
            }
        }
        // lane holds D[px = nbase+ni*16+quad*4+t][o = obase+mbase+mi*16+r]
        #pragma unroll
        for(int ni=0; ni<4; ni++)
            #pragma unroll
            for(int mi=0; mi<2; mi++){
                int o = obase + mbase + mi*16 + r;
                int px = nbase + ni*16 + quad*4;
                f32x4 a = acc[ni*2+mi];
                unsigned lo = ((unsigned)f2b(a[1]) << 16) | f2b(a[0]);
                unsigned hi = ((unsigned)f2b(a[3]) << 16) | f2b(a[2]);
                *(uint2*)&op[(size_t)o*NPIX + px] = make_uint2(lo, hi);
            }
    }
}

// ---------------------------------------------------------------------------
// K2: per (b,h): full 48x48 Gram of S=[q;k] (conv outputs, bf16) via MFMA.
// grid (32 pchunk, 8 h, 8 b).  LDS 25.3 KB -> 6 blocks/CU.
// ---------------------------------------------------------------------------
__global__ __launch_bounds__(256) void k2_gram(const u16* __restrict__ qkv_pre,
        const float* __restrict__ wdw, float* __restrict__ G){
    __shared__ __align__(16) u16 Sl[48*SPAD];   // 25,344 B; reused as R[4][1536] f32
    const int tid = threadIdx.x;
    const int pc = blockIdx.x, h = blockIdx.y, b = blockIdx.z;
    const int lane = tid & 63, w = tid >> 6;
    const int r = lane & 15, quad = lane >> 4;
    f32x4 acc[6];
    { f32x4 z = {0.f,0.f,0.f,0.f}; for(int i=0;i<6;i++) acc[i]=z; }
    for(int chunk = 0; chunk < 2; chunk++){
        if(chunk) __syncthreads();     // prev MFMA reads of Sl done
        for(int it = 0; it < 6; it++){
            int t = tid + it*256;                 // 0..1535
            int c48 = t >> 5, oct = t & 31;
            int isK = (c48 >= CH);
            int c = isK ? (c48 - CH) : c48;
            int ch = (isK ? DIM : 0) + h*CH + c;
            const u16* base = qkv_pre + ((size_t)b*QKVC + ch)*NPIX;
            const float* wv = wdw + ch*9;
            int py = pc*4 + chunk*2 + (oct >> 4);
            int px0 = (oct & 15)*8;
            float o_[8];
            #pragma unroll
            for(int i=0;i<8;i++) o_[i]=0.f;
            #pragma unroll
            for(int ky=0;ky<3;ky++){
                int ry = py + 2*ky - 2;
                if(ry < 0 || ry >= IH) continue;
                conv_row8(base + ry*IW, px0, wv[ky*3], wv[ky*3+1], wv[ky*3+2], o_);
            }
            bf16x8 v;
            #pragma unroll
            for(int i=0;i<8;i++) v[i] = (short)f2b(o_[i]);
            *(bf16x8*)&Sl[c48*SPAD + oct*8] = v;   // col = within-chunk px idx
        }
        __syncthreads();               // Sl ready
        #pragma unroll
        for(int kk = 0; kk < 2; kk++){
            const int k0 = w*64 + kk*32 + quad*8;
            bf16x8 f0 = *(const bf16x8*)&Sl[(     r)*SPAD + k0];
            bf16x8 f1 = *(const bf16x8*)&Sl[(16 + r)*SPAD + k0];
            bf16x8 f2 = *(const bf16x8*)&Sl[(32 + r)*SPAD + k0];
            acc[0] = __builtin_amdgcn_mfma_f32_16x16x32_bf16(f0, f0, acc[0], 0,0,0);
            acc[1] = __builtin_amdgcn_mfma_f32_16x16x32_bf16(f0, f1, acc[1], 0,0,0);
            acc[2] = __builtin_amdgcn_mfma_f32_16x16x32_bf16(f0, f2, acc[2], 0,0,0);
            acc[3] = __builtin_amdgcn_mfma_f32_16x16x32_bf16(f1, f1, acc[3], 0,0,0);
            acc[4] = __builtin_amdgcn_mfma_f32_16x16x32_bf16(f1, f2, acc[4], 0,0,0);
            acc[5] = __builtin_amdgcn_mfma_f32_16x16x32_bf16(f2, f2, acc[5], 0,0,0);
        }
    }
    __syncthreads();                   // all MFMA reads of Sl done
    float* R = (float*)Sl;             // R[w][tile][lane][t]
    #pragma unroll
    for(int tile=0; tile<6; tile++)
        *(f32x4*)&R[(w*6 + tile)*256 + lane*4] = acc[tile];
    __syncthreads();
    float* Gb = G + (size_t)(b*NH + h)*48*48;
    #pragma unroll
    for(int i=0; i<6; i++){
        int idx = tid + i*256;                    // 0..1535
        int tile = idx >> 8, rem = idx & 255;
        int ln = rem >> 2, t = rem & 3;
        float s = R[idx] + R[1536 + idx] + R[2*1536 + idx] + R[3*1536 + idx];
        int ti = (tile<3) ? 0 : ((tile<5) ? 1 : 2);
        int tj = (tile<3) ? tile : ((tile<5) ? (tile-2) : 2);
        int c = ti*16 + (ln >> 4)*4 + t;
        int d = tj*16 + (ln & 15);
        atomicAdd(&Gb[c*48 + d], s);
    }
}

// ---------------------------------------------------------------------------
// K4: v_post = dw-conv(v_pre), vectorized; written over the q-slot (ch 0..191)
// of qkv_pre (k2 already consumed q). grid (8 bands, 96 chpairs, 8 b).
// ---------------------------------------------------------------------------
__global__ __launch_bounds__(256) void k4_vconv(u16* __restrict__ qkv_pre,
        const float* __restrict__ wdw){
    const int tid = threadIdx.x;
    const int oct = tid & 15, pyl = tid >> 4;
    const int band = blockIdx.x, cp = blockIdx.y, b = blockIdx.z;
    const int py = band*16 + pyl, px0 = oct*8;
    #pragma unroll
    for(int j=0;j<2;j++){
        int ch = cp*2 + j;
        const u16* base = qkv_pre + ((size_t)b*QKVC + 2*DIM + ch)*NPIX;
        const float* wv = wdw + (2*DIM + ch)*9;
        float o_[8];
        #pragma unroll
        for(int i=0;i<8;i++) o_[i]=0.f;
        #pragma unroll
        for(int ky=0;ky<3;ky++){
            int ry = py + 2*ky - 2;
            if(ry < 0 || ry >= IH) continue;
            conv_row8(base + ry*IW, px0, wv[ky*3], wv[ky*3+1], wv[ky*3+2], o_);
        }
        bf16x8 v;
        #pragma unroll
        for(int i=0;i<8;i++) v[i] = (short)f2b(o_[i]);
        *(bf16x8*)&qkv_pre[((size_t)b*QKVC + ch)*NPIX + py*IW + px0] = v;
    }
}

// ---------------------------------------------------------------------------
// K3: softmax(Gqk/(|q||k|)*T) folded with Wproj -> M[b][o][hd] (bf16). grid 8.
// norms come from the qq/kk diagonals of the 48x48 Gram.
// ---------------------------------------------------------------------------
__global__ __launch_bounds__(256) void k3_attn(const float* __restrict__ G,
        const float* __restrict__ temp, const float* __restrict__ wproj,
        u16* __restrict__ M){
    __shared__ float attn[NH][CH][CH];
    __shared__ float nq[DIM], nk[DIM];
    const int b = blockIdx.x, tid = threadIdx.x;
    const float* Gb = G + (size_t)b*NH*48*48;
    if(tid < DIM){
        int h = tid / CH, c = tid % CH;
        const float* g = Gb + (size_t)h*48*48;
        nq[tid] = fmaxf(sqrtf(g[c*48 + c]), 1e-12f);
        nk[tid] = fmaxf(sqrtf(g[(CH+c)*48 + (CH+c)]), 1e-12f);
    }
    __syncthreads();
    if(tid < DIM){
        int h = tid / CH, c = tid % CH;
        float t = temp[h];
        const float* g = Gb + (size_t)h*48*48 + c*48 + CH;   // q row c vs k cols
        float row[CH];
        float mx = -1e30f;
        #pragma unroll
        for(int d=0; d<CH; d++){
            float v = g[d] / (nq[tid]*nk[h*CH+d]) * t;
            row[d]=v; mx = fmaxf(mx,v);
        }
        float sum=0.f;
        #pragma unroll
        for(int d=0;d<CH;d++){ row[d]=expf(row[d]-mx); sum+=row[d]; }
        float inv = 1.f/sum;
        #pragma unroll
        for(int d=0;d<CH;d++) attn[h][c][d] = row[d]*inv;
    }
    __syncthreads();
    u16* Mb = M + (size_t)b*DIM*DIM;
    for(int i = tid; i < DIM*DIM; i += 256){
        int o = i / DIM, hd = i % DIM;
        int h = hd / CH, d = hd % CH;
        float s = 0.f;
        #pragma unroll
        for(int c=0;c<CH;c++)
            s += wproj[o*DIM + h*CH + c] * attn[h][c][d];
        Mb[i] = f2b(s);   // same rounding k5's staging used to apply
    }
}

// ---------------------------------------------------------------------------
// K5: out[b][o][p] = sum_hd M[b][o][hd]*v_post[b][hd][p].  Pure MFMA GEMM.
// vl staged once (51.2 KB -> 3 blocks/CU); M bf16 fragments direct from
// global (L2-resident, 73.7 KB/batch). No loop barriers. grid (128,8).
// ---------------------------------------------------------------------------
__global__ __launch_bounds__(256) void k5_out(const u16* __restrict__ qkv_pre,
        const u16* __restrict__ M, float* __restrict__ out){
    __shared__ __align__(16) u16 vl[128*PAD];   // 51.2 KB
    const int tid = threadIdx.x;
    const int py = blockIdx.x, b = blockIdx.y;
    const int p0 = py*IW;
    // stage v^T: vl[px][ch] from v_post (q-slot, ch 0..191)
    {
        const int px = tid & 127, half = tid >> 7;
        const u16* vb = qkv_pre + (size_t)b*QKVC*NPIX + p0 + px;
        for(int cg = 0; cg < 12; cg++){
            int cb = half*96 + cg*8;
            bf16x8 v;
            #pragma unroll
            for(int j=0;j<8;j++) v[j] = (short)vb[(size_t)(cb+j)*NPIX];
            *(bf16x8*)&vl[px*PAD + cb] = v;
        }
    }
    __syncthreads();
    const int lane = tid & 63, w = tid >> 6;
    const int r = lane & 15, quad = lane >> 4;
    const int mbase = (w & 1)*32, nbase = (w >> 1)*64;
    const u16* Mb = M + (size_t)b*DIM*DIM;
    for(int ot = 0; ot < 3; ot++){
        const int obase = ot*64;
        f32x4 acc[8];
        { f32x4 z = {0.f,0.f,0.f,0.f}; for(int i=0;i<8;i++) acc[i]=z; }
        const u16* m0 = Mb + (size_t)(obase + mbase + r)*DIM;
        const u16* m1 = m0 + 16*DIM;
        #pragma unroll
        for(int kk = 0; kk < 6; kk++){
            const int k0 = kk*32 + quad*8;
            bf16x8 a0 = *(const bf16x8*)&m0[k0];
            bf16x8 a1 = *(const bf16x8*)&m1[k0];
            #pragma unroll
            for(int ni=0; ni<4; ni++){
                bf16x8 bb = *(const bf16x8*)&vl[(nbase + ni*16 + r)*PAD + k0];
                acc[ni*2+0] = __builtin_amdgcn_mfma_f32_16x16x32_bf16(a0, bb, acc[ni*2+0], 0,0,0);
                acc[ni*2+1] = __builtin_amdgcn_mfma_f32_16x16x32_bf16(a1, bb, acc[ni*2+1], 0,0,0);
            }
        }
        float* op = out + ((size_t)b*DIM + obase)*NPIX + p0;
        #pragma unroll
        for(int ni=0; ni<4; ni++)
            #pragma unroll
            for(int mi=0; mi<2; mi++){
                int o_loc = mbase + mi*16 + quad*4;
                int p_loc = nbase + ni*16 + r;
                #pragma unroll
                for(int t=0;t<4;t++)
                    op[(size_t)(o_loc+t)*NPIX + p_loc] = acc[ni*2+mi][t];
            }
    }
}

// ---------------------------------------------------------------------------
extern "C" void kernel_launch(void* const* d_in, const int* in_sizes, int n_in,
                              void* d_out, int out_size, void* d_ws, size_t ws_size,
                              hipStream_t stream){
    const float* x     = (const float*)d_in[0];
    const float* wqkv  = (const float*)d_in[1];
    const float* wdw   = (const float*)d_in[2];
    const float* wproj = (const float*)d_in[3];
    const float* temp  = (const float*)d_in[4];
    float* out = (float*)d_out;

    char* ws = (char*)d_ws;
    u16* qkv_pre = (u16*)ws;                                     // 151 MB
    size_t off = (size_t)BATCH*QKVC*NPIX*sizeof(u16);
    float* G  = (float*)(ws + off); off += (size_t)BATCH*NH*48*48*4;
    u16* M    = (u16*)(ws + off);   off += (size_t)BATCH*DIM*DIM*2;
    u16* wb   = (u16*)(ws + off);   off += (size_t)QKVC*DIM*2;

    hipMemsetAsync(G, 0, (size_t)BATCH*NH*48*48*sizeof(float), stream);

    k0_wcvt<<<108, 256, 0, stream>>>(wqkv, wb);
    k1_qkv <<<dim3(128, BATCH), 256, 0, stream>>>(x, wb, qkv_pre);
    k2_gram<<<dim3(32, NH, BATCH), 256, 0, stream>>>(qkv_pre, wdw, G);
    // k4 overwrites q-slot with v_post -- must run AFTER k2 consumed q.
    k4_vconv<<<dim3(8, 96, BATCH), 256, 0, stream>>>(qkv_pre, wdw);
    k3_attn<<<BATCH, 256, 0, stream>>>(G, temp, wproj, M);
    k5_out <<<dim3(128, BATCH), 256, 0, stream>>>(qkv_pre, M, out);
}